// Round 1
// baseline (490.381 us; speedup 1.0000x reference)
//
#include <hip/hip_runtime.h>
#include <hip/hip_bf16.h>
#include <cmath>

// Problem constants (from reference): S=16384, IN_DIM=1024, D=6400, BINS=20
#define S_DIM 16384
#define K_DIM 1024
#define D_DIM 6400
#define NBINS 20
#define BM 128
#define BN 128
#define BK 32

using half_t = _Float16;
using half8  = __attribute__((ext_vector_type(8))) _Float16;
using f32x4  = __attribute__((ext_vector_type(4))) float;

// ---------------- fp32 -> fp16 convert (elementwise, float4 in / 8B out) ---
__global__ void cvt_f32_f16(const float* __restrict__ s, half_t* __restrict__ d, int n4) {
  int i = blockIdx.x * blockDim.x + threadIdx.x;
  if (i >= n4) return;
  float4 v = ((const float4*)s)[i];
  union { half_t h[4]; short4 s4; } u;
  u.h[0] = (half_t)v.x; u.h[1] = (half_t)v.y; u.h[2] = (half_t)v.z; u.h[3] = (half_t)v.w;
  ((short4*)d)[i] = u.s4;
}

// ---------------- fused GEMM + histogram ----------------------------------
// Block: 256 threads = 4 waves, each wave owns a 64x64 quadrant of a 128x128
// C-tile (4x4 grid of 16x16x32 f16 MFMAs). B = W is [D][K] i.e. B^T layout,
// same staging pattern as A. LDS layouts match global_load_lds's
// wave-uniform-base + lane*16 rule exactly (no padding possible).
// Histogram: accumulator values are binned straight into an LDS histogram
// (128 cols x 20 bins), flushed once per block with global int atomics.
template <bool DMA>
__global__ __launch_bounds__(256) void gemm_hist_kernel(
    const float* __restrict__ xf, const float* __restrict__ wf,
    const half_t* __restrict__ xh, const half_t* __restrict__ wh,
    const float* __restrict__ mins, const float* __restrict__ maxs,
    int* __restrict__ ghist)
{
  __shared__ __align__(16) half_t ldsA[BM * BK];   // 8 KB
  __shared__ __align__(16) half_t ldsB[BN * BK];   // 8 KB
  __shared__ int shist[BN * NBINS];                // 10 KB

  const int t     = threadIdx.x;
  const int lane  = t & 63;
  const int wv    = t >> 6;
  const int waveM = wv >> 1;       // 0..1
  const int waveN = wv & 1;        // 0..1
  const int l16   = lane & 15;
  const int quad  = lane >> 4;
  const int colBase = blockIdx.x * BN;

  for (int i = t; i < BN * NBINS; i += 256) shist[i] = 0;

  // Each thread's accumulator columns depend only on nt (col = lane&15):
  // preload min/max/scale for its 4 columns.
  float mn[4], mx[4], inv[4];
  int lcol[4];
#pragma unroll
  for (int nt = 0; nt < 4; ++nt) {
    int lc = waveN * 64 + nt * 16 + l16;
    lcol[nt] = lc;
    float a = mins[colBase + lc], b = maxs[colBase + lc];
    mn[nt] = a; mx[nt] = b;
    inv[nt] = (float)NBINS / (b - a);
  }

  for (int rt = blockIdx.y; rt < S_DIM / BM; rt += gridDim.y) {
    const int rowBase = rt * BM;
    f32x4 acc[4][4];
#pragma unroll
    for (int mt = 0; mt < 4; ++mt)
#pragma unroll
      for (int nt = 0; nt < 4; ++nt)
        acc[mt][nt] = (f32x4){0.f, 0.f, 0.f, 0.f};

    for (int kt = 0; kt < K_DIM; kt += BK) {
      __syncthreads();   // prev tile consumed; safe to overwrite LDS
      if constexpr (DMA) {
#pragma unroll
        for (int i = 0; i < 2; ++i) {
          const int seg = t + i * 256;                 // 16B segment index
          const int row = seg >> 2, kofs = (seg & 3) * 8;
          const half_t* ga = xh + (size_t)(rowBase + row) * K_DIM + kt + kofs;
          __builtin_amdgcn_global_load_lds(
              (const __attribute__((address_space(1))) void*)ga,
              (__attribute__((address_space(3))) void*)&ldsA[i * 2048 + wv * 512],
              16, 0, 0);
        }
#pragma unroll
        for (int i = 0; i < 2; ++i) {
          const int seg = t + i * 256;
          const int row = seg >> 2, kofs = (seg & 3) * 8;
          const half_t* gb = wh + (size_t)(colBase + row) * K_DIM + kt + kofs;
          __builtin_amdgcn_global_load_lds(
              (const __attribute__((address_space(1))) void*)gb,
              (__attribute__((address_space(3))) void*)&ldsB[i * 2048 + wv * 512],
              16, 0, 0);
        }
      } else {
        // fallback: read fp32 directly, convert, ds_write (ws too small)
#pragma unroll
        for (int i = 0; i < 2; ++i) {
          const int seg = t + i * 256;
          const int row = seg >> 2, kofs = (seg & 3) * 8;
          const float* ga = xf + (size_t)(rowBase + row) * K_DIM + kt + kofs;
          float4 v0 = ((const float4*)ga)[0];
          float4 v1 = ((const float4*)ga)[1];
          half8 h = { (half_t)v0.x, (half_t)v0.y, (half_t)v0.z, (half_t)v0.w,
                      (half_t)v1.x, (half_t)v1.y, (half_t)v1.z, (half_t)v1.w };
          *(half8*)&ldsA[seg * 8] = h;
          const float* gb = wf + (size_t)(colBase + row) * K_DIM + kt + kofs;
          float4 u0 = ((const float4*)gb)[0];
          float4 u1 = ((const float4*)gb)[1];
          half8 g = { (half_t)u0.x, (half_t)u0.y, (half_t)u0.z, (half_t)u0.w,
                      (half_t)u1.x, (half_t)u1.y, (half_t)u1.z, (half_t)u1.w };
          *(half8*)&ldsB[seg * 8] = g;
        }
      }
      __syncthreads();   // barrier drains vmcnt -> staged data visible

      half8 aF[4], bF[4];
#pragma unroll
      for (int mt = 0; mt < 4; ++mt)
        aF[mt] = *(const half8*)&ldsA[(waveM * 64 + mt * 16 + l16) * BK + quad * 8];
#pragma unroll
      for (int nt = 0; nt < 4; ++nt)
        bF[nt] = *(const half8*)&ldsB[(waveN * 64 + nt * 16 + l16) * BK + quad * 8];
#pragma unroll
      for (int mt = 0; mt < 4; ++mt)
#pragma unroll
        for (int nt = 0; nt < 4; ++nt)
          acc[mt][nt] = __builtin_amdgcn_mfma_f32_16x16x32_f16(
              aF[mt], bF[nt], acc[mt][nt], 0, 0, 0);
    }

    // Epilogue: bin this row-tile's projections into the LDS histogram.
    // torch.histc semantics: count iff min<=v<=max; floor((v-min)/w*bins),
    // clipped to [0, bins-1] (v==max lands in last bin).
#pragma unroll
    for (int nt = 0; nt < 4; ++nt) {
      const float a = mn[nt], b = mx[nt], s = inv[nt];
      int* colHist = &shist[lcol[nt] * NBINS];
#pragma unroll
      for (int mt = 0; mt < 4; ++mt) {
#pragma unroll
        for (int r = 0; r < 4; ++r) {
          float v = acc[mt][nt][r];
          if (v >= a && v <= b) {
            int bin = (int)floorf((v - a) * s);
            bin = bin < 0 ? 0 : (bin > NBINS - 1 ? NBINS - 1 : bin);
            atomicAdd(&colHist[bin], 1);
          }
        }
      }
    }
  }

  __syncthreads();
  for (int i = t; i < BN * NBINS; i += 256) {
    int v = shist[i];
    if (v) atomicAdd(&ghist[colBase * NBINS + i], v);
  }
}

// ---------------- L2 normalize per group of 20 bins (in place) ------------
__global__ void normalize_kernel(const int* __restrict__ hist, float* __restrict__ out) {
  int g = blockIdx.x * blockDim.x + threadIdx.x;
  if (g >= D_DIM) return;
  const int base = g * NBINS;
  float v[NBINS];
  float ss = 0.f;
#pragma unroll
  for (int i = 0; i < NBINS; ++i) { v[i] = (float)hist[base + i]; ss += v[i] * v[i]; }
  float sc = 1.0f / fmaxf(sqrtf(ss), 1e-12f);
#pragma unroll
  for (int i = 0; i < NBINS; ++i) out[base + i] = v[i] * sc;
}

extern "C" void kernel_launch(void* const* d_in, const int* in_sizes, int n_in,
                              void* d_out, int out_size, void* d_ws, size_t ws_size,
                              hipStream_t stream) {
  const float* x    = (const float*)d_in[0];
  const float* W    = (const float*)d_in[1];
  const float* mins = (const float*)d_in[2];
  const float* maxs = (const float*)d_in[3];
  float* out = (float*)d_out;

  // d_out doubles as the int histogram accumulator; zero it (re-poisoned 0xAA).
  hipMemsetAsync(d_out, 0, (size_t)out_size * sizeof(float), stream);

  const size_t xh_elems = (size_t)S_DIM * K_DIM;
  const size_t wh_elems = (size_t)D_DIM * K_DIM;
  const size_t need = (xh_elems + wh_elems) * sizeof(half_t);

  dim3 grid(D_DIM / BN, 64);   // 50 col-tiles x 64 row-groups = 3200 blocks

  if (ws_size >= need) {
    half_t* xh = (half_t*)d_ws;
    half_t* wh = xh + xh_elems;
    int nx4 = (int)(xh_elems / 4), nw4 = (int)(wh_elems / 4);
    cvt_f32_f16<<<(nx4 + 255) / 256, 256, 0, stream>>>(x, xh, nx4);
    cvt_f32_f16<<<(nw4 + 255) / 256, 256, 0, stream>>>(W, wh, nw4);
    gemm_hist_kernel<true><<<grid, 256, 0, stream>>>(
        nullptr, nullptr, xh, wh, mins, maxs, (int*)d_out);
  } else {
    gemm_hist_kernel<false><<<grid, 256, 0, stream>>>(
        x, W, nullptr, nullptr, mins, maxs, (int*)d_out);
  }

  normalize_kernel<<<(D_DIM + 255) / 256, 256, 0, stream>>>((int*)d_out, out);
}

// Round 2
// 485.737 us; speedup vs baseline: 1.0096x; 1.0096x over previous
//
#include <hip/hip_runtime.h>
#include <hip/hip_bf16.h>
#include <cmath>

// Problem constants (from reference): S=16384, IN_DIM=1024, D=6400, BINS=20
#define S_DIM 16384
#define K_DIM 1024
#define D_DIM 6400
#define NBINS 20
#define HSTRIDE 21   // shist column stride (pad 20->21: spreads atomic banks)
#define BM 128
#define BN 128
#define BK 32

using half_t = _Float16;
using half8  = __attribute__((ext_vector_type(8))) _Float16;
using f32x4  = __attribute__((ext_vector_type(4))) float;

// ---------------- fp32 -> fp16 convert (elementwise, float4 in / 8B out) ---
__global__ void cvt_f32_f16(const float* __restrict__ s, half_t* __restrict__ d, int n4) {
  int i = blockIdx.x * blockDim.x + threadIdx.x;
  if (i >= n4) return;
  float4 v = ((const float4*)s)[i];
  union { half_t h[4]; short4 s4; } u;
  u.h[0] = (half_t)v.x; u.h[1] = (half_t)v.y; u.h[2] = (half_t)v.z; u.h[3] = (half_t)v.w;
  ((short4*)d)[i] = u.s4;
}

// ---------------- fused GEMM + histogram ----------------------------------
// 256 threads = 4 waves; 128x128 C-tile; 16x16x32 f16 MFMA, 4x4 per wave.
//
// LDS swizzle: logical (row m, 16B k-chunk q) lives at slot m*4 + (q ^ ((m>>1)&3)).
// global_load_lds forces slot = wave-uniform base + lane (16B units), so the
// staging loop permutes each lane's GLOBAL k-chunk instead (inverse map).
// Result: fragment ds_read_b128 hits all 8 bank-groups exactly 2x per
// quarter-wave (minimum aliasing = conflict-free) instead of 8-way.
template <bool DMA>
__global__ __launch_bounds__(256) void gemm_hist_kernel(
    const float* __restrict__ xf, const float* __restrict__ wf,
    const half_t* __restrict__ xh, const half_t* __restrict__ wh,
    const float* __restrict__ mins, const float* __restrict__ maxs,
    int* __restrict__ ghist)
{
  __shared__ __align__(16) half_t ldsA[BM * BK];   // 8 KB
  __shared__ __align__(16) half_t ldsB[BN * BK];   // 8 KB
  __shared__ int shist[BN * HSTRIDE];              // 10.5 KB

  const int t     = threadIdx.x;
  const int lane  = t & 63;
  const int wv    = t >> 6;
  const int waveM = wv >> 1;       // 0..1
  const int waveN = wv & 1;        // 0..1
  const int l16   = lane & 15;
  const int quad  = lane >> 4;
  const int colBase = blockIdx.x * BN;

  for (int i = t; i < BN * HSTRIDE; i += 256) shist[i] = 0;

  // Per-thread accumulator columns depend only on nt (col = lane&15).
  float mn[4], mx[4], inv[4];
  int lcol[4];
#pragma unroll
  for (int nt = 0; nt < 4; ++nt) {
    int lc = waveN * 64 + nt * 16 + l16;
    lcol[nt] = lc;
    float a = mins[colBase + lc], b = maxs[colBase + lc];
    mn[nt] = a; mx[nt] = b;
    inv[nt] = (float)NBINS / (b - a);
  }

  // Swizzled fragment read offsets (precomputed, in half_t elements).
  // slot(m,q) = m*4 + (q ^ ((m>>1)&3)); element offset = slot*8.
  int aOff[4], bOff[4];
#pragma unroll
  for (int mt = 0; mt < 4; ++mt) {
    int m = waveM * 64 + mt * 16 + l16;
    aOff[mt] = (m * 4 + (quad ^ ((m >> 1) & 3))) * 8;
  }
#pragma unroll
  for (int nt = 0; nt < 4; ++nt) {
    int n = waveN * 64 + nt * 16 + l16;
    bOff[nt] = (n * 4 + (quad ^ ((n >> 1) & 3))) * 8;
  }

  for (int rt = blockIdx.y; rt < S_DIM / BM; rt += gridDim.y) {
    const int rowBase = rt * BM;
    f32x4 acc[4][4];
#pragma unroll
    for (int mt = 0; mt < 4; ++mt)
#pragma unroll
      for (int nt = 0; nt < 4; ++nt)
        acc[mt][nt] = (f32x4){0.f, 0.f, 0.f, 0.f};

    for (int kt = 0; kt < K_DIM; kt += BK) {
      __syncthreads();   // prev tile consumed; safe to overwrite LDS
      if constexpr (DMA) {
#pragma unroll
        for (int i = 0; i < 2; ++i) {
          const int seg = t + i * 256;                 // LDS 16B-slot index
          const int row = seg >> 2;
          const int kch = (seg & 3) ^ ((row >> 1) & 3);  // inverse swizzle
          const half_t* ga = xh + (size_t)(rowBase + row) * K_DIM + kt + kch * 8;
          __builtin_amdgcn_global_load_lds(
              (const __attribute__((address_space(1))) void*)ga,
              (__attribute__((address_space(3))) void*)&ldsA[i * 2048 + wv * 512],
              16, 0, 0);
        }
#pragma unroll
        for (int i = 0; i < 2; ++i) {
          const int seg = t + i * 256;
          const int row = seg >> 2;
          const int kch = (seg & 3) ^ ((row >> 1) & 3);
          const half_t* gb = wh + (size_t)(colBase + row) * K_DIM + kt + kch * 8;
          __builtin_amdgcn_global_load_lds(
              (const __attribute__((address_space(1))) void*)gb,
              (__attribute__((address_space(3))) void*)&ldsB[i * 2048 + wv * 512],
              16, 0, 0);
        }
      } else {
        // fallback: read fp32 directly, convert, ds_write (ws too small)
#pragma unroll
        for (int i = 0; i < 2; ++i) {
          const int seg = t + i * 256;
          const int row = seg >> 2;
          const int kch = (seg & 3) ^ ((row >> 1) & 3);
          const float* ga = xf + (size_t)(rowBase + row) * K_DIM + kt + kch * 8;
          float4 v0 = ((const float4*)ga)[0];
          float4 v1 = ((const float4*)ga)[1];
          half8 h = { (half_t)v0.x, (half_t)v0.y, (half_t)v0.z, (half_t)v0.w,
                      (half_t)v1.x, (half_t)v1.y, (half_t)v1.z, (half_t)v1.w };
          *(half8*)&ldsA[seg * 8] = h;
          const float* gb = wf + (size_t)(colBase + row) * K_DIM + kt + kch * 8;
          float4 u0 = ((const float4*)gb)[0];
          float4 u1 = ((const float4*)gb)[1];
          half8 g = { (half_t)u0.x, (half_t)u0.y, (half_t)u0.z, (half_t)u0.w,
                      (half_t)u1.x, (half_t)u1.y, (half_t)u1.z, (half_t)u1.w };
          *(half8*)&ldsB[seg * 8] = g;
        }
      }
      __syncthreads();   // barrier drains vmcnt -> staged data visible

      half8 aF[4], bF[4];
#pragma unroll
      for (int mt = 0; mt < 4; ++mt)
        aF[mt] = *(const half8*)&ldsA[aOff[mt]];
#pragma unroll
      for (int nt = 0; nt < 4; ++nt)
        bF[nt] = *(const half8*)&ldsB[bOff[nt]];
#pragma unroll
      for (int mt = 0; mt < 4; ++mt)
#pragma unroll
        for (int nt = 0; nt < 4; ++nt)
          acc[mt][nt] = __builtin_amdgcn_mfma_f32_16x16x32_f16(
              aF[mt], bF[nt], acc[mt][nt], 0, 0, 0);
    }

    // Epilogue: bin this row-tile's projections into the LDS histogram.
    // torch.histc semantics: count iff min<=v<=max; floor((v-min)/w*bins),
    // clipped to [0, bins-1] (v==max lands in last bin).
#pragma unroll
    for (int nt = 0; nt < 4; ++nt) {
      const float a = mn[nt], b = mx[nt], s = inv[nt];
      int* colHist = &shist[lcol[nt] * HSTRIDE];
#pragma unroll
      for (int mt = 0; mt < 4; ++mt) {
#pragma unroll
        for (int r = 0; r < 4; ++r) {
          float v = acc[mt][nt][r];
          if (v >= a && v <= b) {
            int bin = (int)floorf((v - a) * s);
            bin = bin < 0 ? 0 : (bin > NBINS - 1 ? NBINS - 1 : bin);
            atomicAdd(&colHist[bin], 1);
          }
        }
      }
    }
  }

  __syncthreads();
  for (int i = t; i < BN * NBINS; i += 256) {
    int col = i / NBINS, bin = i % NBINS;
    int v = shist[col * HSTRIDE + bin];
    if (v) atomicAdd(&ghist[colBase * NBINS + i], v);
  }
}

// ---------------- L2 normalize per group of 20 bins (in place) ------------
__global__ void normalize_kernel(const int* __restrict__ hist, float* __restrict__ out) {
  int g = blockIdx.x * blockDim.x + threadIdx.x;
  if (g >= D_DIM) return;
  const int base = g * NBINS;
  float v[NBINS];
  float ss = 0.f;
#pragma unroll
  for (int i = 0; i < NBINS; ++i) { v[i] = (float)hist[base + i]; ss += v[i] * v[i]; }
  float sc = 1.0f / fmaxf(sqrtf(ss), 1e-12f);
#pragma unroll
  for (int i = 0; i < NBINS; ++i) out[base + i] = v[i] * sc;
}

extern "C" void kernel_launch(void* const* d_in, const int* in_sizes, int n_in,
                              void* d_out, int out_size, void* d_ws, size_t ws_size,
                              hipStream_t stream) {
  const float* x    = (const float*)d_in[0];
  const float* W    = (const float*)d_in[1];
  const float* mins = (const float*)d_in[2];
  const float* maxs = (const float*)d_in[3];
  float* out = (float*)d_out;

  // d_out doubles as the int histogram accumulator; zero it (re-poisoned 0xAA).
  hipMemsetAsync(d_out, 0, (size_t)out_size * sizeof(float), stream);

  const size_t xh_elems = (size_t)S_DIM * K_DIM;
  const size_t wh_elems = (size_t)D_DIM * K_DIM;
  const size_t need = (xh_elems + wh_elems) * sizeof(half_t);

  dim3 grid(D_DIM / BN, 64);   // 50 col-tiles x 64 row-groups = 3200 blocks

  if (ws_size >= need) {
    half_t* xh = (half_t*)d_ws;
    half_t* wh = xh + xh_elems;
    int nx4 = (int)(xh_elems / 4), nw4 = (int)(wh_elems / 4);
    cvt_f32_f16<<<(nx4 + 255) / 256, 256, 0, stream>>>(x, xh, nx4);
    cvt_f32_f16<<<(nw4 + 255) / 256, 256, 0, stream>>>(W, wh, nw4);
    gemm_hist_kernel<true><<<grid, 256, 0, stream>>>(
        nullptr, nullptr, xh, wh, mins, maxs, (int*)d_out);
  } else {
    gemm_hist_kernel<false><<<grid, 256, 0, stream>>>(
        x, W, nullptr, nullptr, mins, maxs, (int*)d_out);
  }

  normalize_kernel<<<(D_DIM + 255) / 256, 256, 0, stream>>>((int*)d_out, out);
}

// Round 3
// 459.002 us; speedup vs baseline: 1.0684x; 1.0582x over previous
//
#include <hip/hip_runtime.h>
#include <hip/hip_bf16.h>
#include <cmath>

// Problem constants (from reference): S=16384, IN_DIM=1024, D=6400, BINS=20
#define S_DIM 16384
#define K_DIM 1024
#define D_DIM 6400
#define NBINS 20
#define HSTRIDE 21   // shist column stride (pad 20->21: spreads atomic banks)
#define BM 128
#define BN 128
#define BK 32

using half_t = _Float16;
using half8  = __attribute__((ext_vector_type(8))) _Float16;
using f32x4  = __attribute__((ext_vector_type(4))) float;

// ---------------- fp32 -> fp16 convert (elementwise, float4 in / 8B out) ---
__global__ void cvt_f32_f16(const float* __restrict__ s, half_t* __restrict__ d, int n4) {
  int i = blockIdx.x * blockDim.x + threadIdx.x;
  if (i >= n4) return;
  float4 v = ((const float4*)s)[i];
  union { half_t h[4]; short4 s4; } u;
  u.h[0] = (half_t)v.x; u.h[1] = (half_t)v.y; u.h[2] = (half_t)v.z; u.h[3] = (half_t)v.w;
  ((short4*)d)[i] = u.s4;
}

// Raw barrier / waitcnt: s_barrier WITHOUT the compiler's vmcnt(0) drain.
// vmcnt retires in issue order (m135); each wave waits only its 4 oldest
// (tile-k) DMAs, then a raw barrier publishes all waves' tile-k LDS writes.
#define VMWAIT(N) __asm__ volatile("s_waitcnt vmcnt(" #N ")" ::: "memory")
#define BAR()     __asm__ volatile("s_barrier" ::: "memory")

#define KSTEP(P)                                                          \
  {                                                                       \
    half8 aF[4], bF[4];                                                   \
    _Pragma("unroll")                                                     \
    for (int mt = 0; mt < 4; ++mt)                                        \
      aF[mt] = *(const half8*)&ldsA[(P) * 4096 + aOff[mt]];               \
    _Pragma("unroll")                                                     \
    for (int nt = 0; nt < 4; ++nt)                                        \
      bF[nt] = *(const half8*)&ldsB[(P) * 4096 + bOff[nt]];               \
    _Pragma("unroll")                                                     \
    for (int mt = 0; mt < 4; ++mt)                                        \
      _Pragma("unroll")                                                   \
      for (int nt = 0; nt < 4; ++nt)                                      \
        acc[mt][nt] = __builtin_amdgcn_mfma_f32_16x16x32_f16(             \
            aF[mt], bF[nt], acc[mt][nt], 0, 0, 0);                        \
  }

// ---------------- fused GEMM + histogram ----------------------------------
// 256 threads = 4 waves; 128x128 C-tile; 16x16x32 f16 MFMA, 4x4 per wave.
// Double-buffered LDS (tile k in buf k&1); DMA for k+1 issued before the
// barrier that consumes k; s_waitcnt vmcnt(4) + raw s_barrier keeps the
// prefetch in flight across the barrier (no vmcnt(0) drain).
// LDS bank swizzle from round 1 retained (slot m*4 + (q ^ ((m>>1)&3))).
template <bool DMA>
__global__ __launch_bounds__(256) void gemm_hist_kernel(
    const float* __restrict__ xf, const float* __restrict__ wf,
    const half_t* __restrict__ xh, const half_t* __restrict__ wh,
    const float* __restrict__ mins, const float* __restrict__ maxs,
    int* __restrict__ ghist)
{
  __shared__ __align__(16) half_t ldsA[2 * 4096];   // 16 KB (2 bufs x 128x32)
  __shared__ __align__(16) half_t ldsB[2 * 4096];   // 16 KB
  __shared__ int shist[BN * HSTRIDE];               // 10.5 KB

  const int t     = threadIdx.x;
  const int lane  = t & 63;
  const int wv    = t >> 6;
  const int waveM = wv >> 1;       // 0..1
  const int waveN = wv & 1;        // 0..1
  const int l16   = lane & 15;
  const int quad  = lane >> 4;
  const int colBase = blockIdx.x * BN;

  for (int i = t; i < BN * HSTRIDE; i += 256) shist[i] = 0;

  // Per-thread accumulator columns depend only on nt (col = lane&15).
  float mn[4], mx[4], inv[4];
  int lcol[4];
#pragma unroll
  for (int nt = 0; nt < 4; ++nt) {
    int lc = waveN * 64 + nt * 16 + l16;
    lcol[nt] = lc;
    float a = mins[colBase + lc], b = maxs[colBase + lc];
    mn[nt] = a; mx[nt] = b;
    inv[nt] = (float)NBINS / (b - a);
  }

  // Swizzled fragment read offsets (half_t elements within one buffer).
  int aOff[4], bOff[4];
#pragma unroll
  for (int mt = 0; mt < 4; ++mt) {
    int m = waveM * 64 + mt * 16 + l16;
    aOff[mt] = (m * 4 + (quad ^ ((m >> 1) & 3))) * 8;
  }
#pragma unroll
  for (int nt = 0; nt < 4; ++nt) {
    int n = waveN * 64 + nt * 16 + l16;
    bOff[nt] = (n * 4 + (quad ^ ((n >> 1) & 3))) * 8;
  }

  // Staging: thread t fetches global chunk (row = t>>2 (+64), kch swizzled)
  // into LDS slot = lane order (global_load_lds wave-uniform-base rule).
  const int  chunk  = (t & 3) ^ ((t >> 3) & 3);   // inverse swizzle
  const size_t thrOfs = (size_t)(t >> 2) * K_DIM + chunk * 8;

  auto issue4 = [&](const half_t* a0, const half_t* a1,
                    const half_t* b0, const half_t* b1, int P) {
    half_t* la = (half_t*)&ldsA[P * 4096 + wv * 512];
    half_t* lb = (half_t*)&ldsB[P * 4096 + wv * 512];
    __builtin_amdgcn_global_load_lds(
        (const __attribute__((address_space(1))) void*)a0,
        (__attribute__((address_space(3))) void*)la, 16, 0, 0);
    __builtin_amdgcn_global_load_lds(
        (const __attribute__((address_space(1))) void*)a1,
        (__attribute__((address_space(3))) void*)(la + 2048), 16, 0, 0);
    __builtin_amdgcn_global_load_lds(
        (const __attribute__((address_space(1))) void*)b0,
        (__attribute__((address_space(3))) void*)lb, 16, 0, 0);
    __builtin_amdgcn_global_load_lds(
        (const __attribute__((address_space(1))) void*)b1,
        (__attribute__((address_space(3))) void*)(lb + 2048), 16, 0, 0);
  };

  for (int rt = blockIdx.y; rt < S_DIM / BM; rt += gridDim.y) {
    const int rowBase = rt * BM;
    f32x4 acc[4][4];
#pragma unroll
    for (int mt = 0; mt < 4; ++mt)
#pragma unroll
      for (int nt = 0; nt < 4; ++nt)
        acc[mt][nt] = (f32x4){0.f, 0.f, 0.f, 0.f};

    if constexpr (DMA) {
      const half_t* aP0 = xh + (size_t)rowBase * K_DIM + thrOfs;
      const half_t* aP1 = aP0 + 64 * K_DIM;
      const half_t* bP0 = wh + (size_t)colBase * K_DIM + thrOfs;
      const half_t* bP1 = bP0 + 64 * K_DIM;

      // prologue: tile0 -> buf0   (prev rt's last barrier guarantees bufs free)
      issue4(aP0, aP1, bP0, bP1, 0);
      aP0 += BK; aP1 += BK; bP0 += BK; bP1 += BK;

      for (int kt = 0; kt < 30; kt += 2) {
        issue4(aP0, aP1, bP0, bP1, 1);            // tile kt+1 -> buf1
        aP0 += BK; aP1 += BK; bP0 += BK; bP1 += BK;
        VMWAIT(4); BAR();                         // tile kt (buf0) ready
        KSTEP(0);
        BAR();                                    // buf0 consumed by all waves
        issue4(aP0, aP1, bP0, bP1, 0);            // tile kt+2 -> buf0
        aP0 += BK; aP1 += BK; bP0 += BK; bP1 += BK;
        VMWAIT(4); BAR();                         // tile kt+1 (buf1) ready
        KSTEP(1);
        BAR();
      }
      issue4(aP0, aP1, bP0, bP1, 1);              // tile31 -> buf1
      VMWAIT(4); BAR();                           // tile30 ready
      KSTEP(0);
      BAR();
      VMWAIT(0); BAR();                           // tile31 ready
      KSTEP(1);
      BAR();
    } else {
      // fallback: fp32 reads + convert + ds_write, classic 2-barrier loop
      for (int kt = 0; kt < K_DIM; kt += BK) {
        __syncthreads();
#pragma unroll
        for (int i = 0; i < 2; ++i) {
          const int seg = t + i * 256;
          const int row = seg >> 2;
          const int kch = (seg & 3) ^ ((row >> 1) & 3);
          const float* ga = xf + (size_t)(rowBase + row) * K_DIM + kt + kch * 8;
          float4 v0 = ((const float4*)ga)[0];
          float4 v1 = ((const float4*)ga)[1];
          half8 h = { (half_t)v0.x, (half_t)v0.y, (half_t)v0.z, (half_t)v0.w,
                      (half_t)v1.x, (half_t)v1.y, (half_t)v1.z, (half_t)v1.w };
          *(half8*)&ldsA[seg * 8] = h;
          const float* gb = wf + (size_t)(colBase + row) * K_DIM + kt + kch * 8;
          float4 u0 = ((const float4*)gb)[0];
          float4 u1 = ((const float4*)gb)[1];
          half8 g = { (half_t)u0.x, (half_t)u0.y, (half_t)u0.z, (half_t)u0.w,
                      (half_t)u1.x, (half_t)u1.y, (half_t)u1.z, (half_t)u1.w };
          *(half8*)&ldsB[seg * 8] = g;
        }
        __syncthreads();
        KSTEP(0);
      }
    }

    // Epilogue: bin this row-tile's projections into the LDS histogram.
    // torch.histc semantics: count iff min<=v<=max; floor((v-min)/w*bins),
    // clipped to [0, bins-1] (v==max lands in last bin).
#pragma unroll
    for (int nt = 0; nt < 4; ++nt) {
      const float a = mn[nt], b = mx[nt], s = inv[nt];
      int* colHist = &shist[lcol[nt] * HSTRIDE];
#pragma unroll
      for (int mt = 0; mt < 4; ++mt) {
#pragma unroll
        for (int r = 0; r < 4; ++r) {
          float v = acc[mt][nt][r];
          if (v >= a && v <= b) {
            int bin = (int)floorf((v - a) * s);
            bin = bin < 0 ? 0 : (bin > NBINS - 1 ? NBINS - 1 : bin);
            atomicAdd(&colHist[bin], 1);
          }
        }
      }
    }
  }

  __syncthreads();
  for (int i = t; i < BN * NBINS; i += 256) {
    int col = i / NBINS, bin = i % NBINS;
    int v = shist[col * HSTRIDE + bin];
    if (v) atomicAdd(&ghist[colBase * NBINS + i], v);
  }
}

// ---------------- L2 normalize per group of 20 bins (in place) ------------
__global__ void normalize_kernel(const int* __restrict__ hist, float* __restrict__ out) {
  int g = blockIdx.x * blockDim.x + threadIdx.x;
  if (g >= D_DIM) return;
  const int base = g * NBINS;
  float v[NBINS];
  float ss = 0.f;
#pragma unroll
  for (int i = 0; i < NBINS; ++i) { v[i] = (float)hist[base + i]; ss += v[i] * v[i]; }
  float sc = 1.0f / fmaxf(sqrtf(ss), 1e-12f);
#pragma unroll
  for (int i = 0; i < NBINS; ++i) out[base + i] = v[i] * sc;
}

extern "C" void kernel_launch(void* const* d_in, const int* in_sizes, int n_in,
                              void* d_out, int out_size, void* d_ws, size_t ws_size,
                              hipStream_t stream) {
  const float* x    = (const float*)d_in[0];
  const float* W    = (const float*)d_in[1];
  const float* mins = (const float*)d_in[2];
  const float* maxs = (const float*)d_in[3];
  float* out = (float*)d_out;

  // d_out doubles as the int histogram accumulator; zero it (re-poisoned 0xAA).
  hipMemsetAsync(d_out, 0, (size_t)out_size * sizeof(float), stream);

  const size_t xh_elems = (size_t)S_DIM * K_DIM;
  const size_t wh_elems = (size_t)D_DIM * K_DIM;
  const size_t need = (xh_elems + wh_elems) * sizeof(half_t);

  dim3 grid(D_DIM / BN, 64);   // 50 col-tiles x 64 row-groups = 3200 blocks

  if (ws_size >= need) {
    half_t* xh = (half_t*)d_ws;
    half_t* wh = xh + xh_elems;
    int nx4 = (int)(xh_elems / 4), nw4 = (int)(wh_elems / 4);
    cvt_f32_f16<<<(nx4 + 255) / 256, 256, 0, stream>>>(x, xh, nx4);
    cvt_f32_f16<<<(nw4 + 255) / 256, 256, 0, stream>>>(W, wh, nw4);
    gemm_hist_kernel<true><<<grid, 256, 0, stream>>>(
        nullptr, nullptr, xh, wh, mins, maxs, (int*)d_out);
  } else {
    gemm_hist_kernel<false><<<grid, 256, 0, stream>>>(
        x, W, nullptr, nullptr, mins, maxs, (int*)d_out);
  }

  normalize_kernel<<<(D_DIM + 255) / 256, 256, 0, stream>>>((int*)d_out, out);
}